// Round 1
// baseline (840.217 us; speedup 1.0000x reference)
//
#include <hip/hip_runtime.h>

// BlockDense: out[b, g*16+h] = relu( sum_w x[b, g*16+w] * W[g, w, h] )
// B=8192, G=1024, w=16, H=16. fp32 in/out. HBM-bound (~1.07 GB @ 6.3 TB/s -> ~170us).
//
// Tiling: block = 256 threads (4 waves) covers BT=64 batch rows x GT=4 groups.
//  - x tile staged to LDS with fully-coalesced float4 loads.
//  - compute: wave wv owns group wv, lane = row -> W reads are wave-uniform
//    (LDS broadcast, ~zero bank bandwidth) instead of 1 KiB/instr scattered.
//  - relu'd outputs written back IN PLACE into the x tile (lane's read region ==
//    lane's write region, bijective -> race-free), then coalesced float4 store.

constexpr int Bv      = 8192;
constexpr int Gv      = 1024;
constexpr int BT      = 64;            // batch rows per block
constexpr int GT      = 4;             // groups per block (== waves per block)
constexpr int XS      = GT * 16 + 4;   // 68 floats: x_s row stride (16B-aligned: 272 B)
constexpr int WSTRIDE = 16 * 16 + 4;   // 260 floats: w_s group stride (16B-aligned: 1040 B)
constexpr int COLS    = Gv * 16;       // 16384 (same for in and out)

__global__ __launch_bounds__(256, 4)
void block_dense_kernel(const float* __restrict__ x,
                        const float* __restrict__ W,
                        float* __restrict__ out) {
    __shared__ float xs[BT * XS];       // 17408 B, doubles as out staging
    __shared__ float ws[GT * WSTRIDE];  // 4160 B

    const int t  = threadIdx.x;
    const int g0 = blockIdx.x * GT;     // first group of tile
    const int b0 = blockIdx.y * BT;     // first batch row of tile

    // ---- stage W tile: GT groups x 256 floats = 256 float4, one per thread ----
    {
        const int gl = t >> 6;          // group-local (0..3)
        const int f4 = t & 63;          // float4 index within group (0..63)
        const float4 v = *reinterpret_cast<const float4*>(
            W + (size_t)(g0 + gl) * 256 + (size_t)f4 * 4);
        *reinterpret_cast<float4*>(&ws[gl * WSTRIDE + f4 * 4]) = v;
    }

    // ---- stage x tile: 64 rows x 64 floats = 1024 float4, 4 per thread ----
    #pragma unroll
    for (int k = 0; k < 4; ++k) {
        const int f   = k * 256 + t;    // float4 index within tile
        const int row = f >> 4;         // 16 float4 per row
        const int c4  = f & 15;
        const float4 v = *reinterpret_cast<const float4*>(
            x + (size_t)(b0 + row) * COLS + (size_t)g0 * 16 + c4 * 4);
        *reinterpret_cast<float4*>(&xs[row * XS + c4 * 4]) = v;
    }
    __syncthreads();

    // ---- compute: wave wv -> group wv; lane -> batch row ----
    {
        const int gl   = t >> 6;        // wave index == group-local index
        const int lane = t & 63;        // row within tile

        float4* xslot = reinterpret_cast<float4*>(&xs[lane * XS + gl * 16]);
        float xr[16];
        #pragma unroll
        for (int k = 0; k < 4; ++k) {
            const float4 v = xslot[k];
            xr[4 * k + 0] = v.x; xr[4 * k + 1] = v.y;
            xr[4 * k + 2] = v.z; xr[4 * k + 3] = v.w;
        }

        float acc[16];
        #pragma unroll
        for (int i = 0; i < 16; ++i) acc[i] = 0.0f;

        const float4* wrow = reinterpret_cast<const float4*>(&ws[gl * WSTRIDE]);
        #pragma unroll
        for (int w = 0; w < 16; ++w) {
            const float xw = xr[w];
            #pragma unroll
            for (int h4 = 0; h4 < 4; ++h4) {
                const float4 wv4 = wrow[w * 4 + h4];   // wave-uniform -> broadcast
                acc[h4 * 4 + 0] = fmaf(xw, wv4.x, acc[h4 * 4 + 0]);
                acc[h4 * 4 + 1] = fmaf(xw, wv4.y, acc[h4 * 4 + 1]);
                acc[h4 * 4 + 2] = fmaf(xw, wv4.z, acc[h4 * 4 + 2]);
                acc[h4 * 4 + 3] = fmaf(xw, wv4.w, acc[h4 * 4 + 3]);
            }
        }

        // relu + write back in place (same slot this lane read from)
        #pragma unroll
        for (int k = 0; k < 4; ++k) {
            float4 v;
            v.x = fmaxf(acc[4 * k + 0], 0.0f);
            v.y = fmaxf(acc[4 * k + 1], 0.0f);
            v.z = fmaxf(acc[4 * k + 2], 0.0f);
            v.w = fmaxf(acc[4 * k + 3], 0.0f);
            xslot[k] = v;
        }
    }
    __syncthreads();

    // ---- store out tile: mirror of x staging, fully coalesced ----
    #pragma unroll
    for (int k = 0; k < 4; ++k) {
        const int f   = k * 256 + t;
        const int row = f >> 4;
        const int c4  = f & 15;
        const float4 v = *reinterpret_cast<const float4*>(&xs[row * XS + c4 * 4]);
        *reinterpret_cast<float4*>(
            out + (size_t)(b0 + row) * COLS + (size_t)g0 * 16 + c4 * 4) = v;
    }
}

extern "C" void kernel_launch(void* const* d_in, const int* in_sizes, int n_in,
                              void* d_out, int out_size, void* d_ws, size_t ws_size,
                              hipStream_t stream) {
    const float* x = (const float*)d_in[0];   // (8192, 16384) fp32
    const float* W = (const float*)d_in[1];   // (1024, 16, 16) fp32
    float* out = (float*)d_out;               // (8192, 16384) fp32

    dim3 grid(Gv / GT, Bv / BT);              // (256, 128)
    dim3 block(256);
    block_dense_kernel<<<grid, block, 0, stream>>>(x, W, out);
}